// Round 4
// baseline (360.005 us; speedup 1.0000x reference)
//
#include <hip/hip_runtime.h>
#include <hip/hip_cooperative_groups.h>
#include <math.h>

#define NMODES 6400
#define TB     128                // 2 waves per block
#define MPT    10                 // modes per thread (5 float2 pairs)
#define NPAIR  5
#define MG     5                  // mode groups: TB*MPT*MG == NMODES
#define BATCH  6                  // samples per inner batch
#define TC     42                 // samples per time-chunk (22050 = 525*42)
#define GRID   1024               // 4 blocks/CU: LDS 87KB/160KB -> coop-launch valid

namespace cg = cooperative_groups;

typedef float v2f __attribute__((ext_vector_type(2)));

static __device__ __forceinline__ float softplusf(float x) {
    return log1pf(expf(-fabsf(x))) + fmaxf(x, 0.0f);
}
static __device__ __forceinline__ float sigmoidf(float x) {
    return 1.0f / (1.0f + expf(-x));
}

// ONE cooperative kernel, four phases separated by grid-wide syncs.
// Phase 0: per-mode constants (identical math to verified round-3 setup),
//          zero out[], zero peak.
// Phase 1: persistent blocks sweep the 2625 (time-chunk x mode-group) tiles;
//          tile body is byte-identical to the verified round-3 accum_kernel.
// Phase 2: grid-stride |max| -> one atomicMax(float-bits) per block.
// Phase 3: grid-stride divide by peak.
__global__ __launch_bounds__(TB) void mega_kernel(
    const float* __restrict__ mu_raw,
    const float* __restrict__ Dmu_raw,
    const float* __restrict__ T0mu_raw,
    const float* __restrict__ Ly_raw,
    const float* __restrict__ xo_raw,
    const float* __restrict__ yo_raw,
    float* __restrict__ wsA,
    float* __restrict__ wsW,
    float* __restrict__ wsS,
    float* __restrict__ wsCW,
    float* __restrict__ wsSW,
    unsigned int* __restrict__ peak,
    float* __restrict__ out, int T)
{
    cg::grid_group grid = cg::this_grid();
    __shared__ __align__(16) float lds[TC][TB + 2];
    __shared__ float red[2];

    const int tid = threadIdx.x;
    const int gt  = blockIdx.x * TB + tid;
    const int GT  = gridDim.x * TB;

    const float  KF     = 1.0f / 44100.0f;
    const double Kd     = 1.0 / 44100.0;
    const double TWO_PI = 6.283185307179586476925286766559;
    const double I2PI   = 0.15915494309189533576888376337251;

    // ---------------- Phase 0: setup + zero ----------------
    for (int i = gt; i < T; i += GT) out[i] = 0.0f;
    if (gt == 0) *peak = 0u;
    if (gt < NMODES) {
        const float PI_F = (float)M_PI;
        const double om2sq = (2.0 * M_PI * 500.0) * (2.0 * M_PI * 500.0);
        const float ALPHA_F  = (float)(3.0 * M_LN10 / om2sq * (om2sq / 6.0));
        const float BETA_F   = (float)(3.0 * M_LN10 / om2sq * (1.0 - 1.0 / 6.0));
        const float MAX_OM_F = (float)(10000.0 * 2.0 * M_PI);
        const float MIN_OM_F = (float)(20.0 * 2.0 * M_PI);
        const float KK_F     = (float)((1.0 / 44100.0) * (1.0 / 44100.0));

        float mu   = (softplusf(mu_raw[0])   + 1e-4f) * 2.43f;
        float Dmu  = (softplusf(Dmu_raw[0])  + 1e-4f) * 0.002452f;
        float T0mu = (softplusf(T0mu_raw[0]) + 1e-4f) * 0.004115f;
        float Ly   = 1.1f + 2.9f * sigmoidf(Ly_raw[0]);
        float xo   = 0.245f + 0.255f * sigmoidf(xo_raw[0]);
        float yo   = __fadd_rn(__fmul_rn(0.51f, Ly),
                               __fmul_rn(__fmul_rn(0.49f, Ly), sigmoidf(yo_raw[0])));

        float mf = (float)(gt / 80 + 1);
        float nf = (float)(gt % 80 + 1);

        float am = __fmul_rn(__fmul_rn(mf, PI_F), 2.0f);
        float bn = __fdiv_rn(__fmul_rn(nf, PI_F), Ly);
        float g1 = __fadd_rn(__fmul_rn(am, am), __fmul_rn(bn, bn));
        float omega_sq = __fadd_rn(__fmul_rn(T0mu, g1),
                                   __fmul_rn(__fmul_rn(Dmu, g1), g1));
        float omega = sqrtf(fmaxf(omega_sq, 0.0f));
        float valid = (omega <= MAX_OM_F && omega >= MIN_OM_F) ? 1.0f : 0.0f;

        float xi_pi = (float)(0.05 * M_PI);
        float yi = __fmul_rn(0.1f, Ly);
        float InW = __fmul_rn(
            cosf(__fmul_rn(__fmul_rn(xi_pi, mf), 2.0f)),
            cosf(__fdiv_rn(__fmul_rn(__fmul_rn(yi, PI_F), nf), Ly)));
        float OutW = __fmul_rn(
            cosf(__fmul_rn(__fmul_rn(__fmul_rn(xo, PI_F), mf), 2.0f)),
            cosf(__fdiv_rn(__fmul_rn(__fmul_rn(yo, PI_F), nf), Ly)));

        float sigma = __fadd_rn(ALPHA_F, __fmul_rn(BETA_F, __fmul_rn(omega, omega)));
        float ms = __fmul_rn(__fmul_rn(__fmul_rn(0.25f, mu), 0.5f), Ly);
        float P = __fmul_rn(
            __fdiv_rn(__fmul_rn(__fmul_rn(__fmul_rn(OutW, InW), KK_F),
                                expf(__fmul_rn(-sigma, KF))),
                      ms),
            valid);
        float den = __fadd_rn(sinf(__fmul_rn(omega, KF)), 1e-8f);
        float A = __fdiv_rn(P, den);

        double th = (double)omega * Kd;
        double dd = exp(-(double)sigma * Kd);
        wsA[gt]  = A;
        wsW[gt]  = omega;
        wsS[gt]  = sigma;
        wsCW[gt] = (float)(dd * cos(th));
        wsSW[gt] = (float)(dd * sin(th));
    }
    grid.sync();

    // ---------------- Phase 1: accumulate tiles ----------------
    const int tchunks = (T + TC - 1) / TC;
    const int NT = tchunks * MG;
    for (int tile = blockIdx.x; tile < NT; tile += gridDim.x) {
        const int t0   = (tile % tchunks) * TC;
        const int base = (tile / tchunks) * (TB * MPT);

        v2f S[NPAIR], C[NPAIR], CW[NPAIR], SW[NPAIR];
        #pragma unroll
        for (int p = 0; p < NPAIR; ++p) {
            int m = base + p * (TB * 2) + tid * 2;     // even -> 8B aligned
            CW[p] = *(const v2f*)(wsCW + m);
            SW[p] = *(const v2f*)(wsSW + m);
            v2f A  = *(const v2f*)(wsA + m);
            v2f w  = *(const v2f*)(wsW + m);
            v2f sg = *(const v2f*)(wsS + m);
            #pragma unroll
            for (int k = 0; k < 2; ++k) {
                double ph = (double)t0 * (double)w[k] * Kd;
                double q  = rint(ph * I2PI);
                float  r  = (float)fma(-q, TWO_PI, ph);
                float s0, c0;
                __sincosf(r, &s0, &c0);
                float env = A[k] * __expf(-sg[k] * (float)(t0 - 1) * KF);
                S[p][k] = env * s0;
                C[p][k] = env * c0;
            }
        }

        #pragma unroll 1
        for (int it = 0; it < TC; it += BATCH) {
            #pragma unroll
            for (int b = 0; b < BATCH; ++b) {
                // per-thread (10-mode) partial for sample t0+it+b
                v2f s01 = S[0] + S[1];
                v2f s23 = S[2] + S[3];
                v2f sp  = (s01 + s23) + S[4];
                lds[it + b][tid] = sp[0] + sp[1];
                // advance all phasors one step (packed: 4 pk-ops per pair)
                #pragma unroll
                for (int p = 0; p < NPAIR; ++p) {
                    v2f nS = __builtin_elementwise_fma(S[p], CW[p], C[p] * SW[p]);
                    v2f nC = __builtin_elementwise_fma(C[p], CW[p], -(S[p] * SW[p]));
                    S[p] = nS;
                    C[p] = nC;
                }
            }
        }
        __syncthreads();

        const int wv   = tid >> 6;
        const int lane = tid & 63;
        if (lane < TC / 2) {
            int s = wv * (TC / 2) + lane;          // wave 0: 0..20, wave 1: 21..41
            v2f z = {0.0f, 0.0f};
            #pragma unroll
            for (int r = 0; r < TB / 2; ++r)
                z += *(const v2f*)&lds[s][2 * r];
            int t = t0 + s;
            if (t < T) atomicAdd(&out[t], z[0] + z[1]);
        }
        __syncthreads();                           // protect lds for next tile
    }
    grid.sync();

    // ---------------- Phase 2: global |max| ----------------
    const int npairs = (T + 1) >> 1;
    float mx = 0.0f;
    for (int i = gt; i < npairs; i += GT) {
        if (2 * i + 1 < T) {
            v2f v = *(const v2f*)(out + 2 * i);
            mx = fmaxf(mx, fmaxf(fabsf(v[0]), fabsf(v[1])));
        } else {
            mx = fmaxf(mx, fabsf(out[2 * i]));
        }
    }
    #pragma unroll
    for (int off = 32; off > 0; off >>= 1)
        mx = fmaxf(mx, __shfl_xor(mx, off, 64));
    if ((tid & 63) == 0) red[tid >> 6] = mx;
    __syncthreads();
    if (tid == 0) {
        float m = fmaxf(red[0], red[1]);
        if (m > 0.0f) atomicMax(peak, __float_as_uint(m));
    }
    grid.sync();

    // ---------------- Phase 3: normalize ----------------
    float pk = __uint_as_float(
        __hip_atomic_load(peak, __ATOMIC_RELAXED, __HIP_MEMORY_SCOPE_AGENT)) + 1e-8f;
    for (int i = gt; i < npairs; i += GT) {
        if (2 * i + 1 < T) {
            v2f v = *(const v2f*)(out + 2 * i);
            v[0] = __fdiv_rn(v[0], pk);
            v[1] = __fdiv_rn(v[1], pk);
            *(v2f*)(out + 2 * i) = v;
        } else {
            out[2 * i] = __fdiv_rn(out[2 * i], pk);
        }
    }
}

extern "C" void kernel_launch(void* const* d_in, const int* in_sizes, int n_in,
                              void* d_out, int out_size, void* d_ws, size_t ws_size,
                              hipStream_t stream)
{
    const float* mu   = (const float*)d_in[0];
    const float* Dmu  = (const float*)d_in[1];
    const float* T0mu = (const float*)d_in[2];
    const float* Lyr  = (const float*)d_in[3];
    const float* xor_ = (const float*)d_in[4];
    const float* yor_ = (const float*)d_in[5];
    float* out = (float*)d_out;

    float* ws   = (float*)d_ws;
    float* wsA  = ws;
    float* wsW  = ws + NMODES;
    float* wsS  = ws + 2 * NMODES;
    float* wsCW = ws + 3 * NMODES;
    float* wsSW = ws + 4 * NMODES;
    unsigned int* peak = (unsigned int*)(ws + 5 * NMODES);

    int T = out_size;

    void* args[] = {
        (void*)&mu, (void*)&Dmu, (void*)&T0mu, (void*)&Lyr, (void*)&xor_,
        (void*)&yor_, (void*)&wsA, (void*)&wsW, (void*)&wsS, (void*)&wsCW,
        (void*)&wsSW, (void*)&peak, (void*)&out, (void*)&T
    };
    hipLaunchCooperativeKernel((void*)mega_kernel, dim3(GRID), dim3(TB),
                               args, 0, stream);
}

// Round 5
// 188.486 us; speedup vs baseline: 1.9100x; 1.9100x over previous
//
#include <hip/hip_runtime.h>
#include <math.h>

#define NMODES 6400
#define TB     128                // 2 waves per block
#define MPT    10                 // modes per thread (5 float2 pairs)
#define NPAIR  5
#define MG     5                  // mode groups: TB*MPT*MG == NMODES
#define BATCH  6                  // samples per inner batch
#define TC     42                 // samples per time-chunk (22050 = 525*42)

typedef float v2f __attribute__((ext_vector_type(2)));

static __device__ __forceinline__ float softplusf(float x) {
    return log1pf(expf(-fabsf(x))) + fmaxf(x, 0.0f);
}
static __device__ __forceinline__ float sigmoidf(float x) {
    return 1.0f / (1.0f + expf(-x));
}

// Per-mode constants + stride-zero of out + zero of the done counter.
// Math byte-identical to the round-3 verified setup.
__global__ void setup_zero_kernel(const float* __restrict__ mu_raw,
                                  const float* __restrict__ Dmu_raw,
                                  const float* __restrict__ T0mu_raw,
                                  const float* __restrict__ Ly_raw,
                                  const float* __restrict__ xo_raw,
                                  const float* __restrict__ yo_raw,
                                  float* __restrict__ wsA,
                                  float* __restrict__ wsW,
                                  float* __restrict__ wsS,
                                  float* __restrict__ wsCW,
                                  float* __restrict__ wsSW,
                                  unsigned int* __restrict__ done,
                                  float* __restrict__ out, int T)
{
    int id = blockIdx.x * blockDim.x + threadIdx.x;
    int gsz = gridDim.x * blockDim.x;
    for (int i = id; i < T; i += gsz) out[i] = 0.0f;
    if (id == 0) *done = 0u;
    if (id >= NMODES) return;

    const float KF   = 1.0f / 44100.0f;
    const float PI_F = (float)M_PI;
    const double om2sq = (2.0 * M_PI * 500.0) * (2.0 * M_PI * 500.0);
    const float ALPHA_F  = (float)(3.0 * M_LN10 / om2sq * (om2sq / 6.0));
    const float BETA_F   = (float)(3.0 * M_LN10 / om2sq * (1.0 - 1.0 / 6.0));
    const float MAX_OM_F = (float)(10000.0 * 2.0 * M_PI);
    const float MIN_OM_F = (float)(20.0 * 2.0 * M_PI);
    const float KK_F     = (float)((1.0 / 44100.0) * (1.0 / 44100.0));

    float mu   = (softplusf(mu_raw[0])   + 1e-4f) * 2.43f;
    float Dmu  = (softplusf(Dmu_raw[0])  + 1e-4f) * 0.002452f;
    float T0mu = (softplusf(T0mu_raw[0]) + 1e-4f) * 0.004115f;
    float Ly   = 1.1f + 2.9f * sigmoidf(Ly_raw[0]);
    float xo   = 0.245f + 0.255f * sigmoidf(xo_raw[0]);
    float yo   = __fadd_rn(__fmul_rn(0.51f, Ly),
                           __fmul_rn(__fmul_rn(0.49f, Ly), sigmoidf(yo_raw[0])));

    float mf = (float)(id / 80 + 1);
    float nf = (float)(id % 80 + 1);

    float am = __fmul_rn(__fmul_rn(mf, PI_F), 2.0f);
    float bn = __fdiv_rn(__fmul_rn(nf, PI_F), Ly);
    float g1 = __fadd_rn(__fmul_rn(am, am), __fmul_rn(bn, bn));
    float omega_sq = __fadd_rn(__fmul_rn(T0mu, g1),
                               __fmul_rn(__fmul_rn(Dmu, g1), g1));
    float omega = sqrtf(fmaxf(omega_sq, 0.0f));
    float valid = (omega <= MAX_OM_F && omega >= MIN_OM_F) ? 1.0f : 0.0f;

    float xi_pi = (float)(0.05 * M_PI);
    float yi = __fmul_rn(0.1f, Ly);
    float InW = __fmul_rn(
        cosf(__fmul_rn(__fmul_rn(xi_pi, mf), 2.0f)),
        cosf(__fdiv_rn(__fmul_rn(__fmul_rn(yi, PI_F), nf), Ly)));
    float OutW = __fmul_rn(
        cosf(__fmul_rn(__fmul_rn(__fmul_rn(xo, PI_F), mf), 2.0f)),
        cosf(__fdiv_rn(__fmul_rn(__fmul_rn(yo, PI_F), nf), Ly)));

    float sigma = __fadd_rn(ALPHA_F, __fmul_rn(BETA_F, __fmul_rn(omega, omega)));
    float ms = __fmul_rn(__fmul_rn(__fmul_rn(0.25f, mu), 0.5f), Ly);
    float P = __fmul_rn(
        __fdiv_rn(__fmul_rn(__fmul_rn(__fmul_rn(OutW, InW), KK_F),
                            expf(__fmul_rn(-sigma, KF))),
                  ms),
        valid);
    float den = __fadd_rn(sinf(__fmul_rn(omega, KF)), 1e-8f);
    float A = __fdiv_rn(P, den);

    const double Kd = 1.0 / 44100.0;
    double th = (double)omega * Kd;
    double dd = exp(-(double)sigma * Kd);
    wsA[id]  = A;
    wsW[id]  = omega;
    wsS[id]  = sigma;
    wsCW[id] = (float)(dd * cos(th));
    wsSW[id] = (float)(dd * sin(th));
}

// Round-3 verified accum body, plus last-block finalize (max + normalize).
// Ordering: each block's device-scope atomicAdds to out[] are drained before
// __syncthreads (compiler emits vmcnt(0) before s_barrier); tid 0 then issues
// a release __threadfence() before atomicAdd(done). The block that observes
// old == ntiles-1 acquire-fences and reads out[] with agent-scope loads
// (XCD-non-coherence-safe), so it sees every block's contribution.
__global__ __launch_bounds__(TB) void accum_kernel(
    const float* __restrict__ wsA,
    const float* __restrict__ wsW,
    const float* __restrict__ wsS,
    const float* __restrict__ wsCW,
    const float* __restrict__ wsSW,
    float* out,
    unsigned int* done, int T)
{
    __shared__ __align__(16) float lds[TC][TB + 2];
    __shared__ unsigned int isLast;
    __shared__ float red2[2];

    const int tid  = threadIdx.x;
    const int t0   = blockIdx.x * TC;
    const int base = blockIdx.y * (TB * MPT);

    const float  KF     = 1.0f / 44100.0f;
    const double Kd     = 1.0 / 44100.0;
    const double TWO_PI = 6.283185307179586476925286766559;
    const double I2PI   = 0.15915494309189533576888376337251;

    v2f S[NPAIR], C[NPAIR], CW[NPAIR], SW[NPAIR];
    #pragma unroll
    for (int p = 0; p < NPAIR; ++p) {
        int m = base + p * (TB * 2) + tid * 2;     // even -> 8B aligned
        CW[p] = *(const v2f*)(wsCW + m);
        SW[p] = *(const v2f*)(wsSW + m);
        v2f A  = *(const v2f*)(wsA + m);
        v2f w  = *(const v2f*)(wsW + m);
        v2f sg = *(const v2f*)(wsS + m);
        #pragma unroll
        for (int k = 0; k < 2; ++k) {
            double ph = (double)t0 * (double)w[k] * Kd;
            double q  = rint(ph * I2PI);
            float  r  = (float)fma(-q, TWO_PI, ph);
            float s0, c0;
            __sincosf(r, &s0, &c0);
            float env = A[k] * __expf(-sg[k] * (float)(t0 - 1) * KF);
            S[p][k] = env * s0;
            C[p][k] = env * c0;
        }
    }

    #pragma unroll 1
    for (int it = 0; it < TC; it += BATCH) {
        #pragma unroll
        for (int b = 0; b < BATCH; ++b) {
            // per-thread (10-mode) partial for sample t0+it+b
            v2f s01 = S[0] + S[1];
            v2f s23 = S[2] + S[3];
            v2f sp  = (s01 + s23) + S[4];
            lds[it + b][tid] = sp[0] + sp[1];
            // advance all phasors one step (packed: 4 pk-ops per pair)
            #pragma unroll
            for (int p = 0; p < NPAIR; ++p) {
                v2f nS = __builtin_elementwise_fma(S[p], CW[p], C[p] * SW[p]);
                v2f nC = __builtin_elementwise_fma(C[p], CW[p], -(S[p] * SW[p]));
                S[p] = nS;
                C[p] = nC;
            }
        }
    }
    __syncthreads();

    const int wv   = tid >> 6;
    const int lane = tid & 63;
    if (lane < TC / 2) {
        int s = wv * (TC / 2) + lane;              // wave 0: 0..20, wave 1: 21..41
        v2f z = {0.0f, 0.0f};
        #pragma unroll
        for (int r = 0; r < TB / 2; ++r)
            z += *(const v2f*)&lds[s][2 * r];
        int t = t0 + s;
        if (t < T) atomicAdd(&out[t], z[0] + z[1]);
    }
    __syncthreads();                               // drains the atomics (vmcnt 0)

    // ---- last-block finalize: max + normalize ----
    if (tid == 0) {
        __threadfence();                           // release our out[] adds
        unsigned int old = atomicAdd(done, 1u);
        unsigned int ntiles = gridDim.x * gridDim.y;
        isLast = (old == ntiles - 1u) ? 1u : 0u;
    }
    __syncthreads();
    if (isLast) {
        __threadfence();                           // acquire side
        float mx = 0.0f;
        for (int i = tid; i < T; i += TB) {
            float v = __hip_atomic_load(&out[i], __ATOMIC_RELAXED,
                                        __HIP_MEMORY_SCOPE_AGENT);
            mx = fmaxf(mx, fabsf(v));
        }
        #pragma unroll
        for (int off = 32; off > 0; off >>= 1)
            mx = fmaxf(mx, __shfl_xor(mx, off, 64));
        if (lane == 0) red2[wv] = mx;
        __syncthreads();
        float pk = fmaxf(red2[0], red2[1]) + 1e-8f;
        for (int i = tid; i < T; i += TB) {
            float v = __hip_atomic_load(&out[i], __ATOMIC_RELAXED,
                                        __HIP_MEMORY_SCOPE_AGENT);
            out[i] = __fdiv_rn(v, pk);
        }
    }
}

extern "C" void kernel_launch(void* const* d_in, const int* in_sizes, int n_in,
                              void* d_out, int out_size, void* d_ws, size_t ws_size,
                              hipStream_t stream)
{
    const float* mu   = (const float*)d_in[0];
    const float* Dmu  = (const float*)d_in[1];
    const float* T0mu = (const float*)d_in[2];
    const float* Lyr  = (const float*)d_in[3];
    const float* xor_ = (const float*)d_in[4];
    const float* yor_ = (const float*)d_in[5];
    float* out = (float*)d_out;

    float* ws   = (float*)d_ws;
    float* wsA  = ws;
    float* wsW  = ws + NMODES;
    float* wsS  = ws + 2 * NMODES;
    float* wsCW = ws + 3 * NMODES;
    float* wsSW = ws + 4 * NMODES;
    unsigned int* done = (unsigned int*)(ws + 5 * NMODES);

    int T = out_size;
    int tchunks = (T + TC - 1) / TC;

    setup_zero_kernel<<<(NMODES + 255) / 256, 256, 0, stream>>>(
        mu, Dmu, T0mu, Lyr, xor_, yor_, wsA, wsW, wsS, wsCW, wsSW, done, out, T);
    accum_kernel<<<dim3(tchunks, MG), TB, 0, stream>>>(
        wsA, wsW, wsS, wsCW, wsSW, out, done, T);
}

// Round 6
// 147.418 us; speedup vs baseline: 2.4421x; 1.2786x over previous
//
#include <hip/hip_runtime.h>
#include <math.h>

#define NMODES 6400
#define TB     128                // 2 waves per block
#define MPT    10                 // modes per thread per group (5 float2 pairs)
#define NPAIR  5
#define MG     5                  // mode groups looped INSIDE the block
#define BATCH  6                  // samples per inner batch
#define TC     42                 // samples per block (22050 = 525*42)

typedef float v2f __attribute__((ext_vector_type(2)));

static __device__ __forceinline__ float softplusf(float x) {
    return log1pf(expf(-fabsf(x))) + fmaxf(x, 0.0f);
}
static __device__ __forceinline__ float sigmoidf(float x) {
    return 1.0f / (1.0f + expf(-x));
}

// Per-mode constants (math byte-identical to the round-3 verified setup) +
// zero of peak/done. out[] is NOT zeroed: plate_kernel writes each sample
// exactly once.
__global__ void setup_kernel(const float* __restrict__ mu_raw,
                             const float* __restrict__ Dmu_raw,
                             const float* __restrict__ T0mu_raw,
                             const float* __restrict__ Ly_raw,
                             const float* __restrict__ xo_raw,
                             const float* __restrict__ yo_raw,
                             float* __restrict__ wsA,
                             float* __restrict__ wsW,
                             float* __restrict__ wsS,
                             float* __restrict__ wsCW,
                             float* __restrict__ wsSW,
                             unsigned int* __restrict__ peak,
                             unsigned int* __restrict__ done)
{
    int id = blockIdx.x * blockDim.x + threadIdx.x;
    if (id == 0) { *peak = 0u; *done = 0u; }
    if (id >= NMODES) return;

    const float KF   = 1.0f / 44100.0f;
    const float PI_F = (float)M_PI;
    const double om2sq = (2.0 * M_PI * 500.0) * (2.0 * M_PI * 500.0);
    const float ALPHA_F  = (float)(3.0 * M_LN10 / om2sq * (om2sq / 6.0));
    const float BETA_F   = (float)(3.0 * M_LN10 / om2sq * (1.0 - 1.0 / 6.0));
    const float MAX_OM_F = (float)(10000.0 * 2.0 * M_PI);
    const float MIN_OM_F = (float)(20.0 * 2.0 * M_PI);
    const float KK_F     = (float)((1.0 / 44100.0) * (1.0 / 44100.0));

    float mu   = (softplusf(mu_raw[0])   + 1e-4f) * 2.43f;
    float Dmu  = (softplusf(Dmu_raw[0])  + 1e-4f) * 0.002452f;
    float T0mu = (softplusf(T0mu_raw[0]) + 1e-4f) * 0.004115f;
    float Ly   = 1.1f + 2.9f * sigmoidf(Ly_raw[0]);
    float xo   = 0.245f + 0.255f * sigmoidf(xo_raw[0]);
    float yo   = __fadd_rn(__fmul_rn(0.51f, Ly),
                           __fmul_rn(__fmul_rn(0.49f, Ly), sigmoidf(yo_raw[0])));

    float mf = (float)(id / 80 + 1);
    float nf = (float)(id % 80 + 1);

    float am = __fmul_rn(__fmul_rn(mf, PI_F), 2.0f);
    float bn = __fdiv_rn(__fmul_rn(nf, PI_F), Ly);
    float g1 = __fadd_rn(__fmul_rn(am, am), __fmul_rn(bn, bn));
    float omega_sq = __fadd_rn(__fmul_rn(T0mu, g1),
                               __fmul_rn(__fmul_rn(Dmu, g1), g1));
    float omega = sqrtf(fmaxf(omega_sq, 0.0f));
    float valid = (omega <= MAX_OM_F && omega >= MIN_OM_F) ? 1.0f : 0.0f;

    float xi_pi = (float)(0.05 * M_PI);
    float yi = __fmul_rn(0.1f, Ly);
    float InW = __fmul_rn(
        cosf(__fmul_rn(__fmul_rn(xi_pi, mf), 2.0f)),
        cosf(__fdiv_rn(__fmul_rn(__fmul_rn(yi, PI_F), nf), Ly)));
    float OutW = __fmul_rn(
        cosf(__fmul_rn(__fmul_rn(__fmul_rn(xo, PI_F), mf), 2.0f)),
        cosf(__fdiv_rn(__fmul_rn(__fmul_rn(yo, PI_F), nf), Ly)));

    float sigma = __fadd_rn(ALPHA_F, __fmul_rn(BETA_F, __fmul_rn(omega, omega)));
    float ms = __fmul_rn(__fmul_rn(__fmul_rn(0.25f, mu), 0.5f), Ly);
    float P = __fmul_rn(
        __fdiv_rn(__fmul_rn(__fmul_rn(__fmul_rn(OutW, InW), KK_F),
                            expf(__fmul_rn(-sigma, KF))),
                  ms),
        valid);
    float den = __fadd_rn(sinf(__fmul_rn(omega, KF)), 1e-8f);
    float A = __fdiv_rn(P, den);

    const double Kd = 1.0 / 44100.0;
    double th = (double)omega * Kd;
    double dd = exp(-(double)sigma * Kd);
    wsA[id]  = A;
    wsW[id]  = omega;
    wsS[id]  = sigma;
    wsCW[id] = (float)(dd * cos(th));
    wsSW[id] = (float)(dd * sin(th));
}

// Owner-block design: block b owns samples [b*42, b*42+42) and loops over all
// 5 mode-groups, accumulating each sample's total in an owner-lane register.
// Per-group body (phase init, rotation, LDS transpose reduce) is byte-identical
// to the round-3 verified accum. Then: block-local max from registers ->
// one atomicMax(peak) -> release-add(done) -> tid0 spin until done==nblk
// (all 525 blocks structurally co-resident: 22KB LDS -> 7 blocks/CU) ->
// single agent-scope load of peak -> ONE normalized store per sample.
// No out-zero, no out-atomics, no extra dispatches. Replay-safe: done only
// grows past threshold, atomicMax idempotent.
__global__ __launch_bounds__(TB) void plate_kernel(
    const float* __restrict__ wsA,
    const float* __restrict__ wsW,
    const float* __restrict__ wsS,
    const float* __restrict__ wsCW,
    const float* __restrict__ wsSW,
    float* __restrict__ out,
    unsigned int* peak,
    unsigned int* done, int T, int nblk)
{
    __shared__ __align__(16) float lds[TC][TB + 2];
    __shared__ float redmax[2];
    __shared__ float pks;

    const int tid  = threadIdx.x;
    const int t0   = blockIdx.x * TC;
    const int wv   = tid >> 6;
    const int lane = tid & 63;

    const float  KF     = 1.0f / 44100.0f;
    const double Kd     = 1.0 / 44100.0;
    const double TWO_PI = 6.283185307179586476925286766559;
    const double I2PI   = 0.15915494309189533576888376337251;

    const int  s_own = wv * (TC / 2) + lane;       // sample owned by this lane
    const bool own   = (lane < TC / 2) && (t0 + s_own < T);
    float acc = 0.0f;

    #pragma unroll 1
    for (int g = 0; g < MG; ++g) {
        const int base = g * (TB * MPT);

        v2f S[NPAIR], C[NPAIR], CW[NPAIR], SW[NPAIR];
        #pragma unroll
        for (int p = 0; p < NPAIR; ++p) {
            int m = base + p * (TB * 2) + tid * 2;     // even -> 8B aligned
            CW[p] = *(const v2f*)(wsCW + m);
            SW[p] = *(const v2f*)(wsSW + m);
            v2f A  = *(const v2f*)(wsA + m);
            v2f w  = *(const v2f*)(wsW + m);
            v2f sg = *(const v2f*)(wsS + m);
            #pragma unroll
            for (int k = 0; k < 2; ++k) {
                double ph = (double)t0 * (double)w[k] * Kd;
                double q  = rint(ph * I2PI);
                float  r  = (float)fma(-q, TWO_PI, ph);
                float s0, c0;
                __sincosf(r, &s0, &c0);
                float env = A[k] * __expf(-sg[k] * (float)(t0 - 1) * KF);
                S[p][k] = env * s0;
                C[p][k] = env * c0;
            }
        }

        #pragma unroll 1
        for (int it = 0; it < TC; it += BATCH) {
            #pragma unroll
            for (int b = 0; b < BATCH; ++b) {
                // per-thread (10-mode) partial for sample t0+it+b
                v2f s01 = S[0] + S[1];
                v2f s23 = S[2] + S[3];
                v2f sp  = (s01 + s23) + S[4];
                lds[it + b][tid] = sp[0] + sp[1];
                // advance all phasors one step (packed: 4 pk-ops per pair)
                #pragma unroll
                for (int p = 0; p < NPAIR; ++p) {
                    v2f nS = __builtin_elementwise_fma(S[p], CW[p], C[p] * SW[p]);
                    v2f nC = __builtin_elementwise_fma(C[p], CW[p], -(S[p] * SW[p]));
                    S[p] = nS;
                    C[p] = nC;
                }
            }
        }
        __syncthreads();

        if (lane < TC / 2) {
            v2f z = {0.0f, 0.0f};
            #pragma unroll
            for (int r = 0; r < TB / 2; ++r)
                z += *(const v2f*)&lds[s_own][2 * r];
            acc += z[0] + z[1];
        }
        __syncthreads();                           // protect lds for next group
    }

    // ---- block-local |max| from registers ----
    float mx = own ? fabsf(acc) : 0.0f;
    #pragma unroll
    for (int off = 32; off > 0; off >>= 1)
        mx = fmaxf(mx, __shfl_xor(mx, off, 64));
    if (lane == 0) redmax[wv] = mx;
    __syncthreads();

    // ---- rendezvous: contribute max, wait for all blocks, read peak ----
    if (tid == 0) {
        float bm = fmaxf(redmax[0], redmax[1]);
        atomicMax(peak, __float_as_uint(bm));      // device-scope, sign bit 0
        __hip_atomic_fetch_add(done, 1u, __ATOMIC_RELEASE,
                               __HIP_MEMORY_SCOPE_AGENT);
        unsigned int v;
        do {
            __builtin_amdgcn_s_sleep(2);
            v = __hip_atomic_load(done, __ATOMIC_ACQUIRE,
                                  __HIP_MEMORY_SCOPE_AGENT);
        } while (v < (unsigned int)nblk);
        pks = __uint_as_float(__hip_atomic_load(peak, __ATOMIC_RELAXED,
                                                __HIP_MEMORY_SCOPE_AGENT)) + 1e-8f;
    }
    __syncthreads();

    // ---- single normalized store per owned sample ----
    if (own) out[t0 + s_own] = __fdiv_rn(acc, pks);
}

extern "C" void kernel_launch(void* const* d_in, const int* in_sizes, int n_in,
                              void* d_out, int out_size, void* d_ws, size_t ws_size,
                              hipStream_t stream)
{
    const float* mu   = (const float*)d_in[0];
    const float* Dmu  = (const float*)d_in[1];
    const float* T0mu = (const float*)d_in[2];
    const float* Lyr  = (const float*)d_in[3];
    const float* xor_ = (const float*)d_in[4];
    const float* yor_ = (const float*)d_in[5];
    float* out = (float*)d_out;

    float* ws   = (float*)d_ws;
    float* wsA  = ws;
    float* wsW  = ws + NMODES;
    float* wsS  = ws + 2 * NMODES;
    float* wsCW = ws + 3 * NMODES;
    float* wsSW = ws + 4 * NMODES;
    unsigned int* peak = (unsigned int*)(ws + 5 * NMODES);
    unsigned int* done = (unsigned int*)(ws + 5 * NMODES + 1);

    int T = out_size;
    int tchunks = (T + TC - 1) / TC;               // 525 blocks at T=22050

    setup_kernel<<<(NMODES + 255) / 256, 256, 0, stream>>>(
        mu, Dmu, T0mu, Lyr, xor_, yor_, wsA, wsW, wsS, wsCW, wsSW, peak, done);
    plate_kernel<<<tchunks, TB, 0, stream>>>(
        wsA, wsW, wsS, wsCW, wsSW, out, peak, done, T, tchunks);
}